// Round 5
// baseline (143.698 us; speedup 1.0000x reference)
//
#include <hip/hip_runtime.h>

// Shapes (fixed by the problem)
#define BB 8
#define NN 64
#define DD 256
#define PP 256
#define NE 63      // N-1 edges per node
#define EE 4032    // N*(N-1) edges per batch

typedef _Float16 half4 __attribute__((ext_vector_type(4)));
typedef _Float16 half2v __attribute__((ext_vector_type(2)));

// Fused front kernel: 512 blocks (one per (b,n)), 1024 threads (16 waves).
//  (1) each block converts its 1280-half slice of the 655360-half fp16 weight
//      buffer (overlaps with the rest of the block's work),
//  (2) computes the 63 dots s_e = nf[b,dst_e].tgt[b] in-block,
//  (3) produces conc[bn] = [sum s_e*NF[src] | sum s_e*EF | sum s_e*NF[dst]]
//      and Svec[bn] = sum s_e.
__global__ __launch_bounds__(1024) void k_front(const float* __restrict__ nf,
                                                const float* __restrict__ ef,
                                                const int* __restrict__ eidx,
                                                const float* __restrict__ tgt,
                                                const float* __restrict__ Wf0, const float* __restrict__ Wf1,
                                                const float* __restrict__ Wf2, const float* __restrict__ Wi0,
                                                const float* __restrict__ Wi1, const float* __restrict__ Wi2,
                                                _Float16* __restrict__ wh,
                                                float* __restrict__ conc,
                                                float* __restrict__ Svec) {
    __shared__ float s_sh[64];
    __shared__ int src_sh[NE];
    __shared__ int dst_sh[NE];
    __shared__ float Psh[16 * 768];
    int bn = blockIdx.x;           // b*NN + n
    int b = bn >> 6, n = bn & 63;
    int tid = threadIdx.x;
    int lane = tid & 63;
    int h = tid >> 6;              // 0..15

    // --- (1) weight fp16 conversion slice (no barrier needed; consumed by k_mlp) ---
    if (tid < 640) {
        int i = bn * 1280 + tid * 2;   // even, < 655360
        const float* src; int off;
        if (i < 196608)      { src = Wf0; off = 0; }
        else if (i < 262144) { src = Wf1; off = 196608; }
        else if (i < 327680) { src = Wf2; off = 262144; }
        else if (i < 524288) { src = Wi0; off = 327680; }
        else if (i < 589824) { src = Wi1; off = 524288; }
        else                 { src = Wi2; off = 589824; }
        float2 v = *(const float2*)(src + (i - off));
        half2v hh; hh.x = (_Float16)v.x; hh.y = (_Float16)v.y;
        *(half2v*)(wh + i) = hh;
    }

    // --- index load ---
    if (tid < NE) {
        const int* srcp = eidx + (size_t)b * 2 * EE + n * NE;
        src_sh[tid] = srcp[tid];
        dst_sh[tid] = srcp[EE + tid];
    }
    __syncthreads();

    const float4* nf4  = (const float4*)nf;
    const float4* tgt4 = (const float4*)(tgt + (size_t)b * DD);
    float4 c4 = tgt4[lane];

    // --- (2) dots: wave h handles edges [h*4, h*4+4) ---
    int e0 = h * 4, e1 = min(NE, h * 4 + 4);
    for (int e = e0; e < e1; ++e) {
        int d = dst_sh[e];
        float4 a4 = nf4[(size_t)((b << 6) + d) * 64 + lane];
        float p = a4.x * c4.x + a4.y * c4.y + a4.z * c4.z + a4.w * c4.w;
#pragma unroll
        for (int off = 32; off; off >>= 1) p += __shfl_down(p, off, 64);
        if (lane == 0) s_sh[e] = p;
    }
    __syncthreads();

    if (tid < 64) {
        float v = (tid < NE) ? s_sh[tid] : 0.f;
#pragma unroll
        for (int off = 32; off; off >>= 1) v += __shfl_down(v, off, 64);
        if (tid == 0) Svec[bn] = v;
    }

    // --- (3) weighted sums over this wave's e-range ---
    const float4* ef4 = (const float4*)ef;
    size_t efbase = ((size_t)b * EE + (size_t)n * NE) * 64 + lane;
    size_t nfbase = (size_t)(b << 6) * 64 + lane;
    float4 at = {0,0,0,0}, aus = {0,0,0,0}, aud = {0,0,0,0};
#pragma unroll 4
    for (int e = e0; e < e1; ++e) {
        float sv = s_sh[e];
        float4 fe = ef4[efbase + (size_t)e * 64];
        float4 fs = nf4[nfbase + (size_t)src_sh[e] * 64];
        float4 fd = nf4[nfbase + (size_t)dst_sh[e] * 64];
        at.x += sv * fe.x; at.y += sv * fe.y; at.z += sv * fe.z; at.w += sv * fe.w;
        aus.x += sv * fs.x; aus.y += sv * fs.y; aus.z += sv * fs.z; aus.w += sv * fs.w;
        aud.x += sv * fd.x; aud.y += sv * fd.y; aud.z += sv * fd.z; aud.w += sv * fd.w;
    }
    float4* Pf4 = (float4*)Psh;
    Pf4[(size_t)(h * 3 + 0) * 64 + lane] = aus;
    Pf4[(size_t)(h * 3 + 1) * 64 + lane] = at;
    Pf4[(size_t)(h * 3 + 2) * 64 + lane] = aud;
    __syncthreads();

    if (tid < 768) {
        float s = 0.f;
#pragma unroll
        for (int hh = 0; hh < 16; ++hh) s += Psh[hh * 768 + tid];
        conc[(size_t)bn * 768 + tid] = s;
    }
}

// 512 rows; block = 4 rows, 1024 threads.
// Inner: jg = tid&63 (4 cols via half4 weight load), h = tid>>6 (16 k-parts).
// Combine/LN/store: col = tid&255, r2 = tid>>8.
__global__ __launch_bounds__(1024) void k_mlp(const float* __restrict__ conc,
                                              const float* __restrict__ Svec,
                                              const float* __restrict__ nf,
                                              const float* __restrict__ tgt,
                                              const _Float16* __restrict__ Wh,
                                              const float* __restrict__ bf0,
                                              const float* __restrict__ bf1,
                                              const float* __restrict__ bf2,
                                              const float* __restrict__ gam, const float* __restrict__ bet,
                                              const float* __restrict__ bi0,
                                              const float* __restrict__ bi1,
                                              const float* __restrict__ bi2,
                                              float* __restrict__ outp) {
    __shared__ float At[768 * 4];    // conc, transposed [k][r]
    __shared__ float Zt[768 * 4];    // [nf | retrieved | tgt], transposed
    __shared__ float P[16 * 4 * 256];// [h][r][col]
    __shared__ float Ht[256 * 4];    // activations, transposed [k][r]
    __shared__ float red1[16], red2[16];
    int r0 = blockIdx.x * 4;
    int tid = threadIdx.x;
    int jg = tid & 63;
    int h = tid >> 6;                // 0..15 (wave index)
    int col = tid & 255;
    int r2 = tid >> 8;               // 0..3

    const _Float16* Wf0h = Wh;
    const _Float16* Wf1h = Wh + 196608;
    const _Float16* Wf2h = Wh + 262144;
    const _Float16* Wi0h = Wh + 327680;
    const _Float16* Wi1h = Wh + 524288;
    const _Float16* Wi2h = Wh + 589824;

    {
        const float* cp = conc + (size_t)(r0 + r2) * 768;
#pragma unroll
        for (int q = 0; q < 3; ++q) {
            int k = col + q * 256;
            At[k * 4 + r2] = cp[k];
        }
        Zt[col * 4 + r2]         = nf[(size_t)(r0 + r2) * DD + col];
        Zt[(512 + col) * 4 + r2] = tgt[(size_t)((r0 + r2) >> 6) * DD + col];
    }
    float Sv = Svec[r0 + r2];
    __syncthreads();

    auto layer = [&](const float* Xt, int K, const _Float16* __restrict__ W,
                     const float* __restrict__ bias, bool scaleS,
                     float* OUTt, bool store) -> float {
        int kpart = K >> 4;
        const half4* Wp = (const half4*)(W + (size_t)(h * kpart) * 256) + jg;
        const float4* Xp = (const float4*)Xt + h * kpart;
        float4 a0 = {0,0,0,0}, a1 = {0,0,0,0}, a2 = {0,0,0,0}, a3 = {0,0,0,0};
#pragma unroll 8
        for (int k = 0; k < kpart; ++k) {
            half4 wh4 = Wp[(size_t)k * 64];
            float4 x = Xp[k];
            float wx = (float)wh4.x, wy = (float)wh4.y, wz = (float)wh4.z, ww = (float)wh4.w;
            a0.x += x.x * wx; a0.y += x.x * wy; a0.z += x.x * wz; a0.w += x.x * ww;
            a1.x += x.y * wx; a1.y += x.y * wy; a1.z += x.y * wz; a1.w += x.y * ww;
            a2.x += x.z * wx; a2.y += x.z * wy; a2.z += x.z * wz; a2.w += x.z * ww;
            a3.x += x.w * wx; a3.y += x.w * wy; a3.z += x.w * wz; a3.w += x.w * ww;
        }
        float4* Pf4 = (float4*)P;
        Pf4[(size_t)(h * 4 + 0) * 64 + jg] = a0;
        Pf4[(size_t)(h * 4 + 1) * 64 + jg] = a1;
        Pf4[(size_t)(h * 4 + 2) * 64 + jg] = a2;
        Pf4[(size_t)(h * 4 + 3) * 64 + jg] = a3;
        __syncthreads();
        float v = 0.f;
#pragma unroll
        for (int hh = 0; hh < 16; ++hh) v += P[(hh * 4 + r2) * 256 + col];
        v += (scaleS ? Sv : 1.f) * bias[col];
        if (store) {
            OUTt[col * 4 + r2] = v;
        }
        __syncthreads();
        return v;
    };

    layer(At, 768, Wf0h, bf0, true, Ht, true);
    layer(Ht, 256, Wf1h, bf1, true, Ht, true);
    float v = layer(Ht, 256, Wf2h, bf2, true, nullptr, false);

    // LayerNorm across col for each row r2 (4 waves per row)
    {
        float s1 = v, s2 = v * v;
#pragma unroll
        for (int off = 32; off; off >>= 1) {
            s1 += __shfl_down(s1, off, 64);
            s2 += __shfl_down(s2, off, 64);
        }
        int wv = (tid >> 6) & 3;
        if ((tid & 63) == 0) { red1[r2 * 4 + wv] = s1; red2[r2 * 4 + wv] = s2; }
        __syncthreads();
        float sum = red1[r2 * 4] + red1[r2 * 4 + 1] + red1[r2 * 4 + 2] + red1[r2 * 4 + 3];
        float sq  = red2[r2 * 4] + red2[r2 * 4 + 1] + red2[r2 * 4 + 2] + red2[r2 * 4 + 3];
        float mu  = sum * (1.f / 256.f);
        float var = sq * (1.f / 256.f) - mu * mu;
        float inv = rsqrtf(var + 1e-5f);
        Zt[(256 + col) * 4 + r2] = (v - mu) * inv * gam[col] + bet[col];
        __syncthreads();
    }

    layer(Zt, 768, Wi0h, bi0, false, Ht, true);
    layer(Ht, 256, Wi1h, bi1, false, Ht, true);
    float o = layer(Ht, 256, Wi2h, bi2, false, nullptr, false);
    outp[(size_t)(r0 + r2) * 256 + col] = o;
}

extern "C" void kernel_launch(void* const* d_in, const int* in_sizes, int n_in,
                              void* d_out, int out_size, void* d_ws, size_t ws_size,
                              hipStream_t stream) {
    const float* nf  = (const float*)d_in[0];   // (B,N,D)
    const float* ef  = (const float*)d_in[1];   // (B,E,D)
    const float* tgt = (const float*)d_in[2];   // (B,D)
    const int*   ei  = (const int*)d_in[3];     // (B,2,E)
    const float* Wf0 = (const float*)d_in[4];
    const float* bf0 = (const float*)d_in[5];
    const float* Wf1 = (const float*)d_in[6];
    const float* bf1 = (const float*)d_in[7];
    const float* Wf2 = (const float*)d_in[8];
    const float* bf2 = (const float*)d_in[9];
    const float* gam = (const float*)d_in[10];
    const float* bet = (const float*)d_in[11];
    const float* Wi0 = (const float*)d_in[12];
    const float* bi0 = (const float*)d_in[13];
    const float* Wi1 = (const float*)d_in[14];
    const float* bi1 = (const float*)d_in[15];
    const float* Wi2 = (const float*)d_in[16];
    const float* bi2 = (const float*)d_in[17];
    float* out = (float*)d_out;

    float* Svec = (float*)d_ws;                      // 512
    float* conc = Svec + 512;                        // 512*768 = 393216
    _Float16* wh = (_Float16*)(conc + 512 * 768);    // 655360 halfs

    k_front<<<BB * NN, 1024, 0, stream>>>(nf, ef, ei, tgt,
                                          Wf0, Wf1, Wf2, Wi0, Wi1, Wi2,
                                          wh, conc, Svec);
    k_mlp<<<(BB * NN) / 4, 1024, 0, stream>>>(conc, Svec, nf, tgt, wh,
                                              bf0, bf1, bf2, gam, bet,
                                              bi0, bi1, bi2, out);
}